// Round 2
// baseline (8116.087 us; speedup 1.0000x reference)
//
#include <hip/hip_runtime.h>
#include <math.h>

// Problem constants
#define BB 2048
#define LL 100
#define FF 64
#define EE 256
#define DD 256
#define NOUT 3

__device__ __forceinline__ float sigmoidf_(float x) {
    return 1.0f / (1.0f + expf(-x));
}
// tanh via identity 1 - 2/(1+e^{2x}); ~2e-7 abs fp32 error, saturates correctly.
__device__ __forceinline__ float tanhf_(float x) {
    return 1.0f - 2.0f / (1.0f + expf(2.0f * x));
}

// ---------------------------------------------------------------------------
// Encoder step: per-timestep input attention + LSTM cell.
// grid (4 gate-slices, 64 row-groups), 512 threads.
// Reads h from h_in (= enc_out[t-1]), writes h to h_out (= enc_out[t]).
// ---------------------------------------------------------------------------
__global__ __launch_bounds__(512) void enc_step(
    const float* __restrict__ x,
    const float* __restrict__ Wa, const float* __restrict__ ba,
    const float* __restrict__ Wi, const float* __restrict__ Wh,
    const float* __restrict__ be,
    const float* __restrict__ h_in, float* __restrict__ h_out,
    float* __restrict__ c_st, int t, int first)
{
    __shared__ float h_s[32 * 256];
    __shared__ float x_s[32 * 64];
    __shared__ float ein_s[32 * 64];

    const int ns   = blockIdx.x;
    const int row0 = blockIdx.y * 32;
    const int tid  = threadIdx.x;

    if (first) {
        float4 z = make_float4(0.f, 0.f, 0.f, 0.f);
        for (int i = tid; i < 32 * 256 / 4; i += 512) ((float4*)h_s)[i] = z;
    } else {
        const float4* hg = (const float4*)(h_in + (size_t)row0 * 256);
        for (int i = tid; i < 32 * 256 / 4; i += 512) ((float4*)h_s)[i] = hg[i];
    }
    {
        int r = tid >> 4, q = tid & 15;
        ((float4*)(x_s + r * 64))[q] =
            ((const float4*)(x + ((size_t)(row0 + r) * LL + t) * FF))[q];
    }
    __syncthreads();

    const int lane = tid & 63;
    const int w    = tid >> 6;
    const int rb   = w * 4;

    // ---- Phase A: input attention (f = lane) ----
    {
        float a0, a1, a2, a3;
        a0 = a1 = a2 = a3 = ba[lane];
        const float* wp = Wa + lane;
        #pragma unroll 4
        for (int k = 0; k < 64; ++k) {
            float wv = wp[k * 64];
            a0 += x_s[(rb + 0) * 64 + k] * wv;
            a1 += x_s[(rb + 1) * 64 + k] * wv;
            a2 += x_s[(rb + 2) * 64 + k] * wv;
            a3 += x_s[(rb + 3) * 64 + k] * wv;
        }
        if (!first) {
            const float* wph = Wa + 64 * 64 + lane;
            #pragma unroll 4
            for (int k = 0; k < 256; ++k) {
                float wv = wph[k * 64];
                a0 += h_s[(rb + 0) * 256 + k] * wv;
                a1 += h_s[(rb + 1) * 256 + k] * wv;
                a2 += h_s[(rb + 2) * 256 + k] * wv;
                a3 += h_s[(rb + 3) * 256 + k] * wv;
            }
        }
        float acc[4] = { tanhf_(a0), tanhf_(a1), tanhf_(a2), tanhf_(a3) };
        #pragma unroll
        for (int rr = 0; rr < 4; ++rr) {
            float m = acc[rr];
            #pragma unroll
            for (int msk = 32; msk >= 1; msk >>= 1) m = fmaxf(m, __shfl_xor(m, msk, 64));
            float ev = expf(acc[rr] - m);
            float s = ev;
            #pragma unroll
            for (int msk = 32; msk >= 1; msk >>= 1) s += __shfl_xor(s, msk, 64);
            ein_s[(rb + rr) * 64 + lane] = (ev / s) * x_s[(rb + rr) * 64 + lane];
        }
    }
    __syncthreads();

    // ---- Phase B: LSTM gates for unit j, 4 rows ----
    const int j = ns * 64 + lane;
    float ai[4], af[4], ag[4], ao[4];
    {
        float b0 = be[j], b1 = be[256 + j], b2 = be[512 + j], b3 = be[768 + j];
        #pragma unroll
        for (int rr = 0; rr < 4; ++rr) { ai[rr] = b0; af[rr] = b1; ag[rr] = b2; ao[rr] = b3; }
    }
    {
        const float* wp = Wi + j;
        #pragma unroll 4
        for (int k = 0; k < 64; ++k) {
            float w0 = wp[k * 1024], w1 = wp[k * 1024 + 256],
                  w2 = wp[k * 1024 + 512], w3 = wp[k * 1024 + 768];
            #pragma unroll
            for (int rr = 0; rr < 4; ++rr) {
                float e = ein_s[(rb + rr) * 64 + k];
                ai[rr] += e * w0; af[rr] += e * w1; ag[rr] += e * w2; ao[rr] += e * w3;
            }
        }
    }
    if (!first) {
        const float* wp = Wh + j;
        #pragma unroll 4
        for (int k = 0; k < 256; ++k) {
            float w0 = wp[k * 1024], w1 = wp[k * 1024 + 256],
                  w2 = wp[k * 1024 + 512], w3 = wp[k * 1024 + 768];
            #pragma unroll
            for (int rr = 0; rr < 4; ++rr) {
                float hh = h_s[(rb + rr) * 256 + k];
                ai[rr] += hh * w0; af[rr] += hh * w1; ag[rr] += hh * w2; ao[rr] += hh * w3;
            }
        }
    }
    #pragma unroll
    for (int rr = 0; rr < 4; ++rr) {
        size_t ci = (size_t)(row0 + rb + rr) * 256 + j;
        float c_old = first ? 0.f : c_st[ci];
        float gi = sigmoidf_(ai[rr]);
        float gf = sigmoidf_(af[rr]);
        float gg = tanhf_(ag[rr]);
        float go = sigmoidf_(ao[rr]);
        float cn = gf * c_old + gi * gg;
        float hn = go * tanhf_(cn);
        c_st[ci]  = cn;
        h_out[ci] = hn;
    }
}

// ---------------------------------------------------------------------------
// Path A only: pre[l,b,d] = bd[d] + sum_e enc_out[l,b,e] * Wd[e,d]
// ---------------------------------------------------------------------------
__global__ __launch_bounds__(256) void pre_gemm(
    const float* __restrict__ A, const float* __restrict__ Wd,
    const float* __restrict__ bd, float* __restrict__ Cc)
{
    __shared__ float As[32][65];
    __shared__ float Bs[32][64];
    const int n0  = blockIdx.x * 64;
    const int m0  = blockIdx.y * 64;
    const int tid = threadIdx.x;
    const int tx = tid & 15, ty = tid >> 4;
    float acc[4][4] = {};
    for (int k0 = 0; k0 < 256; k0 += 32) {
        #pragma unroll
        for (int s = 0; s < 2; ++s) {
            int v = tid + s * 256;
            int m = v >> 3, kq = (v & 7) * 4;
            float4 a4 = *(const float4*)(A + (size_t)(m0 + m) * 256 + k0 + kq);
            As[kq + 0][m] = a4.x; As[kq + 1][m] = a4.y;
            As[kq + 2][m] = a4.z; As[kq + 3][m] = a4.w;
        }
        #pragma unroll
        for (int s = 0; s < 2; ++s) {
            int v = tid + s * 256;
            int k = v >> 4, nq = (v & 15) * 4;
            *(float4*)&Bs[k][nq] = *(const float4*)(Wd + (size_t)(k0 + k) * 256 + n0 + nq);
        }
        __syncthreads();
        #pragma unroll
        for (int k = 0; k < 32; ++k) {
            float a0 = As[k][ty * 4 + 0], a1 = As[k][ty * 4 + 1],
                  a2 = As[k][ty * 4 + 2], a3 = As[k][ty * 4 + 3];
            float b0 = Bs[k][tx * 4 + 0], b1 = Bs[k][tx * 4 + 1],
                  b2 = Bs[k][tx * 4 + 2], b3 = Bs[k][tx * 4 + 3];
            acc[0][0] += a0 * b0; acc[0][1] += a0 * b1; acc[0][2] += a0 * b2; acc[0][3] += a0 * b3;
            acc[1][0] += a1 * b0; acc[1][1] += a1 * b1; acc[1][2] += a1 * b2; acc[1][3] += a1 * b3;
            acc[2][0] += a2 * b0; acc[2][1] += a2 * b1; acc[2][2] += a2 * b2; acc[2][3] += a2 * b3;
            acc[3][0] += a3 * b0; acc[3][1] += a3 * b1; acc[3][2] += a3 * b2; acc[3][3] += a3 * b3;
        }
        __syncthreads();
    }
    #pragma unroll
    for (int i = 0; i < 4; ++i) {
        size_t m = (size_t)m0 + ty * 4 + i;
        #pragma unroll
        for (int jq = 0; jq < 4; ++jq) {
            int n = n0 + tx * 4 + jq;
            Cc[m * 256 + n] = acc[i][jq] + bd[n];
        }
    }
}

// ---------------------------------------------------------------------------
// Path A: scores -> softmax(L) -> ctx from precomputed pre. Block = 8 rows.
// ---------------------------------------------------------------------------
__global__ __launch_bounds__(256) void attn_ctx(
    const float* __restrict__ pre, const float* __restrict__ enc_out,
    const float* __restrict__ Wd, const float* __restrict__ Wl,
    const float* __restrict__ bl,
    const float* __restrict__ hd, float* __restrict__ ctx, int first)
{
    __shared__ float hd_s[8 * 256];
    __shared__ float hdp_s[8 * 256];
    __shared__ float al_s[8 * 100];
    const int b0  = blockIdx.x * 8;
    const int tid = threadIdx.x;

    if (first) {
        for (int i = tid; i < 8 * 256; i += 256) hdp_s[i] = 0.f;
    } else {
        const float4* hg = (const float4*)(hd + (size_t)b0 * 256);
        for (int i = tid; i < 512; i += 256) ((float4*)hd_s)[i] = hg[i];
        __syncthreads();
        float acc[8] = {};
        const float* wp = Wd + 256 * 256 + tid;
        #pragma unroll 2
        for (int k = 0; k < 256; ++k) {
            float wv = wp[k * 256];
            #pragma unroll
            for (int r = 0; r < 8; ++r) acc[r] += hd_s[r * 256 + k] * wv;
        }
        for (int r = 0; r < 8; ++r) hdp_s[r * 256 + tid] = acc[r];
    }
    __syncthreads();

    const int lane = tid & 63, w = tid >> 6;
    const float blv = bl[0];
    for (int rr = 0; rr < 2; ++rr) {
        const int r = w * 2 + rr;
        const size_t brow = (size_t)(b0 + r) * 256;
        float wl0 = Wl[lane], wl1 = Wl[64 + lane], wl2 = Wl[128 + lane], wl3 = Wl[192 + lane];
        float hp0 = hdp_s[r * 256 + lane],       hp1 = hdp_s[r * 256 + 64 + lane],
              hp2 = hdp_s[r * 256 + 128 + lane], hp3 = hdp_s[r * 256 + 192 + lane];
        for (int l = 0; l < LL; ++l) {
            const float* pr = pre + (size_t)l * (BB * 256) + brow;
            float p = tanhf_(pr[lane]       + hp0) * wl0
                    + tanhf_(pr[64 + lane]  + hp1) * wl1
                    + tanhf_(pr[128 + lane] + hp2) * wl2
                    + tanhf_(pr[192 + lane] + hp3) * wl3;
            #pragma unroll
            for (int msk = 32; msk >= 1; msk >>= 1) p += __shfl_xor(p, msk, 64);
            if (lane == 0) al_s[r * 100 + l] = p + blv;
        }
    }
    __syncthreads();
    if (tid < 8) {
        float m = -1e30f;
        for (int l = 0; l < LL; ++l) m = fmaxf(m, al_s[tid * 100 + l]);
        float s = 0.f;
        for (int l = 0; l < LL; ++l) { float e = expf(al_s[tid * 100 + l] - m); al_s[tid * 100 + l] = e; s += e; }
        float inv = 1.f / s;
        for (int l = 0; l < LL; ++l) al_s[tid * 100 + l] *= inv;
    }
    __syncthreads();
    {
        float acc[8] = {};
        for (int l = 0; l < LL; ++l) {
            const float* er = enc_out + (size_t)l * (BB * 256) + (size_t)b0 * 256 + tid;
            #pragma unroll
            for (int r = 0; r < 8; ++r) acc[r] += al_s[r * 100 + l] * er[r * 256];
        }
        for (int r = 0; r < 8; ++r) ctx[(size_t)(b0 + r) * 256 + tid] = acc[r];
    }
}

// ---------------------------------------------------------------------------
// Path C: fused scores (no pre buffer).
// scores[l*B+b] = bl + sum_n tanh( enc[l,b,:]@WdTop[:,n] + hd@WdBot[:,n] + bd[n] )*Wl[n]
// grid (B/16, L/25), 256 threads (thread = column n).
// ---------------------------------------------------------------------------
#define SF_ROWS 16
#define SF_LCH 25
__global__ __launch_bounds__(256) void scores_fused(
    const float* __restrict__ enc_out, const float* __restrict__ Wd,
    const float* __restrict__ bd,
    const float* __restrict__ Wl, const float* __restrict__ bl,
    const float* __restrict__ hd, float* __restrict__ scores, int first)
{
    __shared__ float enc_s[SF_ROWS * 260];   // padded rows (260*4B, 16B-aligned)
    __shared__ float red_s[4 * SF_ROWS];
    const int b0   = blockIdx.x * SF_ROWS;
    const int l0   = blockIdx.y * SF_LCH;
    const int n    = threadIdx.x;
    const int lane = n & 63, w = n >> 6;

    float hdp[SF_ROWS];
    const float bdn = bd[n];
    if (first) {
        #pragma unroll
        for (int r = 0; r < SF_ROWS; ++r) hdp[r] = bdn;
    } else {
        for (int v = n; v < SF_ROWS * 64; v += 256) {
            int r = v >> 6, q = v & 63;
            *(float4*)&enc_s[r * 260 + q * 4] =
                *(const float4*)(hd + (size_t)(b0 + r) * 256 + q * 4);
        }
        __syncthreads();
        #pragma unroll
        for (int r = 0; r < SF_ROWS; ++r) hdp[r] = bdn;
        const float* wp = Wd + 256 * 256 + n;
        for (int k = 0; k < 256; k += 4) {
            float w0 = wp[k * 256], w1 = wp[(k + 1) * 256],
                  w2 = wp[(k + 2) * 256], w3 = wp[(k + 3) * 256];
            #pragma unroll
            for (int r = 0; r < SF_ROWS; ++r) {
                float4 e4 = *(const float4*)&enc_s[r * 260 + k];
                hdp[r] += e4.x * w0 + e4.y * w1 + e4.z * w2 + e4.w * w3;
            }
        }
        __syncthreads();
    }
    const float wl  = Wl[n];
    const float blv = bl[0];
    for (int li = 0; li < SF_LCH; ++li) {
        const int l = l0 + li;
        for (int v = n; v < SF_ROWS * 64; v += 256) {
            int r = v >> 6, q = v & 63;
            *(float4*)&enc_s[r * 260 + q * 4] =
                *(const float4*)(enc_out + (size_t)l * (BB * 256) + (size_t)(b0 + r) * 256 + q * 4);
        }
        __syncthreads();
        float acc[SF_ROWS];
        #pragma unroll
        for (int r = 0; r < SF_ROWS; ++r) acc[r] = hdp[r];
        const float* wp = Wd + n;
        for (int k = 0; k < 256; k += 4) {
            float w0 = wp[k * 256], w1 = wp[(k + 1) * 256],
                  w2 = wp[(k + 2) * 256], w3 = wp[(k + 3) * 256];
            #pragma unroll
            for (int r = 0; r < SF_ROWS; ++r) {
                float4 e4 = *(const float4*)&enc_s[r * 260 + k];
                acc[r] += e4.x * w0 + e4.y * w1 + e4.z * w2 + e4.w * w3;
            }
        }
        #pragma unroll
        for (int r = 0; r < SF_ROWS; ++r) {
            float p = tanhf_(acc[r]) * wl;
            #pragma unroll
            for (int msk = 32; msk >= 1; msk >>= 1) p += __shfl_xor(p, msk, 64);
            if (lane == 0) red_s[w * SF_ROWS + r] = p;
        }
        __syncthreads();
        if (n < SF_ROWS) {
            scores[(size_t)l * BB + b0 + n] =
                red_s[n] + red_s[SF_ROWS + n] + red_s[2 * SF_ROWS + n] + red_s[3 * SF_ROWS + n] + blv;
        }
        __syncthreads();
    }
}

// ---------------------------------------------------------------------------
// Path C: softmax over L + ctx from scores buffer. Block = 8 rows.
// ---------------------------------------------------------------------------
__global__ __launch_bounds__(256) void softmax_ctx(
    const float* __restrict__ scores, const float* __restrict__ enc_out,
    float* __restrict__ ctx)
{
    __shared__ float al_s[8 * 100];
    const int b0  = blockIdx.x * 8;
    const int tid = threadIdx.x;
    for (int v = tid; v < 800; v += 256) {
        int r = v / 100, l = v - r * 100;
        al_s[r * 100 + l] = scores[(size_t)l * BB + b0 + r];
    }
    __syncthreads();
    if (tid < 8) {
        float m = -1e30f;
        for (int l = 0; l < LL; ++l) m = fmaxf(m, al_s[tid * 100 + l]);
        float s = 0.f;
        for (int l = 0; l < LL; ++l) { float e = expf(al_s[tid * 100 + l] - m); al_s[tid * 100 + l] = e; s += e; }
        float inv = 1.f / s;
        for (int l = 0; l < LL; ++l) al_s[tid * 100 + l] *= inv;
    }
    __syncthreads();
    float acc[8] = {};
    for (int l = 0; l < LL; ++l) {
        const float* er = enc_out + (size_t)l * (BB * 256) + (size_t)b0 * 256 + tid;
        #pragma unroll
        for (int r = 0; r < 8; ++r) acc[r] += al_s[r * 100 + l] * er[r * 256];
    }
    for (int r = 0; r < 8; ++r) ctx[(size_t)(b0 + r) * 256 + tid] = acc[r];
}

// ---------------------------------------------------------------------------
// Decoder LSTM cell. grid (4,64) x 512 threads.
// ---------------------------------------------------------------------------
__global__ __launch_bounds__(512) void dec_step(
    const float* __restrict__ ctxp,
    const float* __restrict__ Wdi, const float* __restrict__ Wdh,
    const float* __restrict__ bdec,
    const float* __restrict__ hd_in, float* __restrict__ hd_out,
    float* __restrict__ c_st, int first)
{
    __shared__ float ct_s[32 * 256];
    __shared__ float hd_s[32 * 256];
    const int ns   = blockIdx.x;
    const int row0 = blockIdx.y * 32;
    const int tid  = threadIdx.x;
    {
        const float4* cg = (const float4*)(ctxp + (size_t)row0 * 256);
        for (int i = tid; i < 2048; i += 512) ((float4*)ct_s)[i] = cg[i];
    }
    if (first) {
        float4 z = make_float4(0.f, 0.f, 0.f, 0.f);
        for (int i = tid; i < 2048; i += 512) ((float4*)hd_s)[i] = z;
    } else {
        const float4* hg = (const float4*)(hd_in + (size_t)row0 * 256);
        for (int i = tid; i < 2048; i += 512) ((float4*)hd_s)[i] = hg[i];
    }
    __syncthreads();
    const int lane = tid & 63, w = tid >> 6, rb = w * 4;
    const int j = ns * 64 + lane;
    float ai[4], af[4], ag[4], ao[4];
    {
        float b0 = bdec[j], b1 = bdec[256 + j], b2 = bdec[512 + j], b3 = bdec[768 + j];
        #pragma unroll
        for (int rr = 0; rr < 4; ++rr) { ai[rr] = b0; af[rr] = b1; ag[rr] = b2; ao[rr] = b3; }
    }
    {
        const float* wp = Wdi + j;
        #pragma unroll 4
        for (int k = 0; k < 256; ++k) {
            float w0 = wp[k * 1024], w1 = wp[k * 1024 + 256],
                  w2 = wp[k * 1024 + 512], w3 = wp[k * 1024 + 768];
            #pragma unroll
            for (int rr = 0; rr < 4; ++rr) {
                float v = ct_s[(rb + rr) * 256 + k];
                ai[rr] += v * w0; af[rr] += v * w1; ag[rr] += v * w2; ao[rr] += v * w3;
            }
        }
    }
    if (!first) {
        const float* wp = Wdh + j;
        #pragma unroll 4
        for (int k = 0; k < 256; ++k) {
            float w0 = wp[k * 1024], w1 = wp[k * 1024 + 256],
                  w2 = wp[k * 1024 + 512], w3 = wp[k * 1024 + 768];
            #pragma unroll
            for (int rr = 0; rr < 4; ++rr) {
                float v = hd_s[(rb + rr) * 256 + k];
                ai[rr] += v * w0; af[rr] += v * w1; ag[rr] += v * w2; ao[rr] += v * w3;
            }
        }
    }
    #pragma unroll
    for (int rr = 0; rr < 4; ++rr) {
        size_t ci = (size_t)(row0 + rb + rr) * 256 + j;
        float c_old = first ? 0.f : c_st[ci];
        float gi = sigmoidf_(ai[rr]);
        float gf = sigmoidf_(af[rr]);
        float gg = tanhf_(ag[rr]);
        float go = sigmoidf_(ao[rr]);
        float cn = gf * c_old + gi * gg;
        float hn = go * tanhf_(cn);
        c_st[ci]  = cn;
        hd_out[ci] = hn;
    }
}

// ---------------------------------------------------------------------------
// Head: fc = tanh(h_d@Wf+bf); out[:,step] = tanh(fc@Wo+bo). Block = 16 rows.
// ---------------------------------------------------------------------------
__global__ __launch_bounds__(256) void head_k(
    const float* __restrict__ hd, const float* __restrict__ Wf,
    const float* __restrict__ bf, const float* __restrict__ Wo,
    const float* __restrict__ bo, float* __restrict__ out, int step)
{
    __shared__ float hd_s[16 * 256];
    __shared__ float fc_s[16 * 128];
    const int b0  = blockIdx.x * 16;
    const int tid = threadIdx.x;
    {
        const float4* hg = (const float4*)(hd + (size_t)b0 * 256);
        for (int i = tid; i < 1024; i += 256) ((float4*)hd_s)[i] = hg[i];
    }
    __syncthreads();
    {
        const int f = tid & 127, rg = tid >> 7;
        float acc[8];
        float bfv = bf[f];
        #pragma unroll
        for (int rr = 0; rr < 8; ++rr) acc[rr] = bfv;
        const float* wp = Wf + f;
        #pragma unroll 2
        for (int k = 0; k < 256; ++k) {
            float wv = wp[k * 128];
            #pragma unroll
            for (int rr = 0; rr < 8; ++rr) acc[rr] += hd_s[(rg * 8 + rr) * 256 + k] * wv;
        }
        for (int rr = 0; rr < 8; ++rr) fc_s[(rg * 8 + rr) * 128 + f] = tanhf_(acc[rr]);
    }
    __syncthreads();
    {
        const int lane = tid & 63, w = tid >> 6;
        const float bov = bo[0];
        #pragma unroll
        for (int rr = 0; rr < 4; ++rr) {
            int r = w * 4 + rr;
            float p = fc_s[r * 128 + lane] * Wo[lane] + fc_s[r * 128 + 64 + lane] * Wo[64 + lane];
            #pragma unroll
            for (int msk = 32; msk >= 1; msk >>= 1) p += __shfl_xor(p, msk, 64);
            if (lane == 0) out[(size_t)(b0 + r) * NOUT + step] = tanhf_(p + bov);
        }
    }
}

extern "C" void kernel_launch(void* const* d_in, const int* in_sizes, int n_in,
                              void* d_out, int out_size, void* d_ws, size_t ws_size,
                              hipStream_t stream)
{
    const float* x    = (const float*)d_in[0];
    const float* Wa   = (const float*)d_in[1];
    const float* ba   = (const float*)d_in[2];
    const float* Wi   = (const float*)d_in[3];
    const float* Wh   = (const float*)d_in[4];
    const float* be   = (const float*)d_in[5];
    const float* Wd   = (const float*)d_in[6];
    const float* bd   = (const float*)d_in[7];
    const float* Wl   = (const float*)d_in[8];
    const float* bl   = (const float*)d_in[9];
    const float* Wdi  = (const float*)d_in[10];
    const float* Wdh  = (const float*)d_in[11];
    const float* bdec = (const float*)d_in[12];
    const float* Wf   = (const float*)d_in[13];
    const float* bf   = (const float*)d_in[14];
    const float* Wo   = (const float*)d_in[15];
    const float* bo   = (const float*)d_in[16];
    float* out = (float*)d_out;

    // ws layout (floats): enc_out | c_enc | hd0 | hd1 | c_d | ctx | scores | [pre]
    const size_t f_enc    = (size_t)LL * BB * EE;     // 52,428,800
    const size_t f_state  = (size_t)BB * EE;          // 524,288
    const size_t f_scores = (size_t)LL * BB;          // 204,800
    const size_t base_f   = f_enc + 5 * f_state + f_scores;

    float* ws      = (float*)d_ws;
    float* enc_out = ws;
    float* c_enc   = enc_out + f_enc;
    float* hd0     = c_enc + f_state;
    float* hd1     = hd0 + f_state;
    float* c_d     = hd1 + f_state;
    float* ctx     = c_d + f_state;
    float* scores  = ctx + f_state;
    float* pre     = scores + f_scores;

    const bool fits_c = ws_size >= base_f * sizeof(float);
    const bool fits_a = ws_size >= (base_f + f_enc) * sizeof(float);
    if (!fits_c) return;   // clean absmax failure (diagnostic), not a fault

    dim3 egrid(4, 64);
    for (int t = 0; t < LL; ++t) {
        const float* h_in = (t == 0) ? enc_out : enc_out + (size_t)(t - 1) * BB * EE;
        float* h_out = enc_out + (size_t)t * BB * EE;
        enc_step<<<egrid, 512, 0, stream>>>(x, Wa, ba, Wi, Wh, be,
                                            h_in, h_out, c_enc, t, t == 0 ? 1 : 0);
    }

    if (fits_a)
        pre_gemm<<<dim3(4, (LL * BB) / 64), 256, 0, stream>>>(enc_out, Wd, bd, pre);

    float* hbuf[2] = { hd0, hd1 };
    for (int s = 0; s < NOUT; ++s) {
        const float* hd_in = (s == 0) ? hd0 : hbuf[(s + 1) & 1];
        float* hd_out = hbuf[s & 1];
        if (fits_a) {
            attn_ctx<<<BB / 8, 256, 0, stream>>>(pre, enc_out, Wd, Wl, bl, hd_in, ctx, s == 0);
        } else {
            scores_fused<<<dim3(BB / SF_ROWS, LL / SF_LCH), 256, 0, stream>>>(
                enc_out, Wd, bd, Wl, bl, hd_in, scores, s == 0);
            softmax_ctx<<<BB / 8, 256, 0, stream>>>(scores, enc_out, ctx);
        }
        dec_step<<<dim3(4, 64), 512, 0, stream>>>(ctx, Wdi, Wdh, bdec, hd_in, hd_out, c_d, s == 0);
        head_k<<<BB / 16, 256, 0, stream>>>(hd_out, Wf, bf, Wo, bo, out, s);
    }
}

// Round 3
// 6062.040 us; speedup vs baseline: 1.3388x; 1.3388x over previous
//
#include <hip/hip_runtime.h>
#include <math.h>

// Problem constants
#define BB 2048
#define LL 100
#define FF 64
#define EE 256
#define DD 256
#define NOUT 3

#define COMP(v, i) ((i) == 0 ? (v).x : (i) == 1 ? (v).y : (i) == 2 ? (v).z : (v).w)

__device__ __forceinline__ float sigmoidf_(float x) {
    return 1.0f / (1.0f + expf(-x));
}
// tanh via identity 1 - 2/(1+e^{2x}); ~2e-7 abs fp32 error, saturates correctly.
__device__ __forceinline__ float tanhf_(float x) {
    return 1.0f - 2.0f / (1.0f + expf(2.0f * x));
}

// ---------------------------------------------------------------------------
// Encoder step: input attention + LSTM cell. grid (4 gate-slices, 64 row-groups
// of 32), 512 threads. Phase B thread = (unit-quad q, gate g): weight loads are
// float4 (consecutive units of one gate); activations come from LDS as
// broadcast ds_read_b128 (all lanes of a wave read the same address).
// Gates are recombined through an LDS staging pass aliased onto h_s.
// ---------------------------------------------------------------------------
__global__ __launch_bounds__(512) void enc_step(
    const float* __restrict__ x,
    const float* __restrict__ Wa, const float* __restrict__ ba,
    const float* __restrict__ Wi, const float* __restrict__ Wh,
    const float* __restrict__ be,
    const float* __restrict__ h_in, float* __restrict__ h_out,
    float* __restrict__ c_st, int t, int first)
{
    __shared__ float h_s[32 * 256];   // h tile; reused as gate staging in epilogue
    __shared__ float x_s[32 * 64];
    __shared__ float ein_s[32 * 64];

    const int ns   = blockIdx.x;
    const int row0 = blockIdx.y * 32;
    const int tid  = threadIdx.x;

    if (!first) {
        const float4* hg = (const float4*)(h_in + (size_t)row0 * 256);
        for (int i = tid; i < 2048; i += 512) ((float4*)h_s)[i] = hg[i];
    }
    {
        int r = tid >> 4, qq = tid & 15;
        ((float4*)(x_s + r * 64))[qq] =
            ((const float4*)(x + ((size_t)(row0 + r) * LL + t) * FF))[qq];
    }
    __syncthreads();

    const int lane = tid & 63;
    const int w    = tid >> 6;    // wave 0..7
    const int rb   = w * 4;       // 4 rows per wave

    // ---- Phase A: input attention (f = lane), duplicated across ns ----
    {
        float a[4];
        {
            float bav = ba[lane];
            a[0] = a[1] = a[2] = a[3] = bav;
        }
        #pragma unroll 4
        for (int k = 0; k < 64; k += 4) {
            float4 xv[4];
            #pragma unroll
            for (int r = 0; r < 4; ++r) xv[r] = *(const float4*)&x_s[(rb + r) * 64 + k];
            #pragma unroll
            for (int kk = 0; kk < 4; ++kk) {
                float wv = Wa[(k + kk) * 64 + lane];
                #pragma unroll
                for (int r = 0; r < 4; ++r) a[r] += COMP(xv[r], kk) * wv;
            }
        }
        if (!first) {
            #pragma unroll 4
            for (int k = 0; k < 256; k += 4) {
                float4 hv[4];
                #pragma unroll
                for (int r = 0; r < 4; ++r) hv[r] = *(const float4*)&h_s[(rb + r) * 256 + k];
                #pragma unroll
                for (int kk = 0; kk < 4; ++kk) {
                    float wv = Wa[(64 + k + kk) * 64 + lane];
                    #pragma unroll
                    for (int r = 0; r < 4; ++r) a[r] += COMP(hv[r], kk) * wv;
                }
            }
        }
        #pragma unroll
        for (int r = 0; r < 4; ++r) {
            float e = tanhf_(a[r]);
            float m = e;
            #pragma unroll
            for (int msk = 32; msk >= 1; msk >>= 1) m = fmaxf(m, __shfl_xor(m, msk, 64));
            float ev = expf(e - m);
            float s = ev;
            #pragma unroll
            for (int msk = 32; msk >= 1; msk >>= 1) s += __shfl_xor(s, msk, 64);
            ein_s[(rb + r) * 64 + lane] = (ev / s) * x_s[(rb + r) * 64 + lane];
        }
    }
    __syncthreads();

    // ---- Phase B: gates. lane -> (unit-quad q, gate g) ----
    const int q = lane & 15, g = lane >> 4;
    const int wcol = g * 256 + ns * 64 + q * 4;   // column of [i|f|g|o] gate matrix
    float acc[4][4];
    {
        float4 b4 = *(const float4*)&be[wcol];
        #pragma unroll
        for (int r = 0; r < 4; ++r) {
            acc[r][0] = b4.x; acc[r][1] = b4.y; acc[r][2] = b4.z; acc[r][3] = b4.w;
        }
    }
    #pragma unroll 2
    for (int k = 0; k < 64; k += 4) {
        float4 ev[4];
        #pragma unroll
        for (int r = 0; r < 4; ++r) ev[r] = *(const float4*)&ein_s[(rb + r) * 64 + k];
        #pragma unroll
        for (int kk = 0; kk < 4; ++kk) {
            float4 wv = *(const float4*)&Wi[(size_t)(k + kk) * 1024 + wcol];
            #pragma unroll
            for (int r = 0; r < 4; ++r) {
                float e = COMP(ev[r], kk);
                acc[r][0] += e * wv.x; acc[r][1] += e * wv.y;
                acc[r][2] += e * wv.z; acc[r][3] += e * wv.w;
            }
        }
    }
    if (!first) {
        #pragma unroll 2
        for (int k = 0; k < 256; k += 4) {
            float4 hv[4];
            #pragma unroll
            for (int r = 0; r < 4; ++r) hv[r] = *(const float4*)&h_s[(rb + r) * 256 + k];
            #pragma unroll
            for (int kk = 0; kk < 4; ++kk) {
                float4 wv = *(const float4*)&Wh[(size_t)(k + kk) * 1024 + wcol];
                #pragma unroll
                for (int r = 0; r < 4; ++r) {
                    float e = COMP(hv[r], kk);
                    acc[r][0] += e * wv.x; acc[r][1] += e * wv.y;
                    acc[r][2] += e * wv.z; acc[r][3] += e * wv.w;
                }
            }
        }
    }
    __syncthreads();              // all h_s / ein_s reads done
    float* gate_s = h_s;          // alias: 4 gates x 32 rows x 64 units = 32 KB
    #pragma unroll
    for (int r = 0; r < 4; ++r)
        *(float4*)&gate_s[g * 2048 + (rb + r) * 64 + q * 4] =
            make_float4(acc[r][0], acc[r][1], acc[r][2], acc[r][3]);
    __syncthreads();

    // epilogue: lane = unit u, wave w handles rows rb..rb+3
    #pragma unroll
    for (int r = 0; r < 4; ++r) {
        int row = rb + r;
        float gi_ = sigmoidf_(gate_s[           row * 64 + lane]);
        float gf_ = sigmoidf_(gate_s[2048 +     row * 64 + lane]);
        float gg_ = tanhf_  (gate_s[4096 +     row * 64 + lane]);
        float go_ = sigmoidf_(gate_s[6144 +     row * 64 + lane]);
        size_t ci = (size_t)(row0 + row) * 256 + ns * 64 + lane;
        float c_old = first ? 0.f : c_st[ci];
        float cn = gf_ * c_old + gi_ * gg_;
        c_st[ci]  = cn;
        h_out[ci] = go_ * tanhf_(cn);
    }
}

// ---------------------------------------------------------------------------
// Fused decoder attention scores.
// scores[l*B+b] = bl + sum_n tanh( enc[l,b,:]@WdTop[:,n] + hd@WdBot[:,n] + bd[n] )*Wl[n]
// grid (B/16, 4), 256 threads. thread = (col-quad cq -> n=cq*4..+3, row-group
// rg=wave -> rows rg*4..+3). One wave spans all 256 n -> single shuffle reduce.
// ---------------------------------------------------------------------------
__global__ __launch_bounds__(256) void scores_fused(
    const float* __restrict__ enc_out, const float* __restrict__ Wd,
    const float* __restrict__ bd,
    const float* __restrict__ Wl, const float* __restrict__ bl,
    const float* __restrict__ hd, float* __restrict__ scores, int first)
{
    __shared__ float enc_s[16 * 256];
    const int b0  = blockIdx.x * 16;
    const int l0  = blockIdx.y * 25;
    const int tid = threadIdx.x;
    const int cq  = tid & 63;      // lane: column quad
    const int rg  = tid >> 6;      // wave: row group
    const int n0  = cq * 4;

    float hdp[4][4];
    {
        float4 bd4 = *(const float4*)&bd[n0];
        #pragma unroll
        for (int r = 0; r < 4; ++r) {
            hdp[r][0] = bd4.x; hdp[r][1] = bd4.y; hdp[r][2] = bd4.z; hdp[r][3] = bd4.w;
        }
    }
    if (!first) {
        for (int v = tid; v < 1024; v += 256) {
            int r = v >> 6, qq = v & 63;
            *(float4*)&enc_s[r * 256 + qq * 4] =
                *(const float4*)(hd + (size_t)(b0 + r) * 256 + qq * 4);
        }
        __syncthreads();
        const float* wb = Wd + 256 * 256;
        #pragma unroll 2
        for (int k = 0; k < 256; k += 4) {
            float4 hv[4];
            #pragma unroll
            for (int r = 0; r < 4; ++r) hv[r] = *(const float4*)&enc_s[(rg * 4 + r) * 256 + k];
            #pragma unroll
            for (int kk = 0; kk < 4; ++kk) {
                float4 wv = *(const float4*)&wb[(size_t)(k + kk) * 256 + n0];
                #pragma unroll
                for (int r = 0; r < 4; ++r) {
                    float e = COMP(hv[r], kk);
                    hdp[r][0] += e * wv.x; hdp[r][1] += e * wv.y;
                    hdp[r][2] += e * wv.z; hdp[r][3] += e * wv.w;
                }
            }
        }
    }
    float4 wl4 = *(const float4*)&Wl[n0];
    const float blv = bl[0];

    for (int li = 0; li < 25; ++li) {
        const int l = l0 + li;
        __syncthreads();
        for (int v = tid; v < 1024; v += 256) {
            int r = v >> 6, qq = v & 63;
            *(float4*)&enc_s[r * 256 + qq * 4] =
                *(const float4*)(enc_out + (size_t)l * (BB * 256) + (size_t)(b0 + r) * 256 + qq * 4);
        }
        __syncthreads();
        float acc[4][4];
        #pragma unroll
        for (int r = 0; r < 4; ++r) {
            acc[r][0] = hdp[r][0]; acc[r][1] = hdp[r][1];
            acc[r][2] = hdp[r][2]; acc[r][3] = hdp[r][3];
        }
        #pragma unroll 2
        for (int k = 0; k < 256; k += 4) {
            float4 ev[4];
            #pragma unroll
            for (int r = 0; r < 4; ++r) ev[r] = *(const float4*)&enc_s[(rg * 4 + r) * 256 + k];
            #pragma unroll
            for (int kk = 0; kk < 4; ++kk) {
                float4 wv = *(const float4*)&Wd[(size_t)(k + kk) * 256 + n0];
                #pragma unroll
                for (int r = 0; r < 4; ++r) {
                    float e = COMP(ev[r], kk);
                    acc[r][0] += e * wv.x; acc[r][1] += e * wv.y;
                    acc[r][2] += e * wv.z; acc[r][3] += e * wv.w;
                }
            }
        }
        #pragma unroll
        for (int r = 0; r < 4; ++r) {
            float p = tanhf_(acc[r][0]) * wl4.x + tanhf_(acc[r][1]) * wl4.y
                    + tanhf_(acc[r][2]) * wl4.z + tanhf_(acc[r][3]) * wl4.w;
            #pragma unroll
            for (int msk = 32; msk >= 1; msk >>= 1) p += __shfl_xor(p, msk, 64);
            if (cq == 0) scores[(size_t)l * BB + b0 + rg * 4 + r] = p + blv;
        }
    }
}

// ---------------------------------------------------------------------------
// softmax over L + ctx from scores buffer. Block = 8 rows.
// ---------------------------------------------------------------------------
__global__ __launch_bounds__(256) void softmax_ctx(
    const float* __restrict__ scores, const float* __restrict__ enc_out,
    float* __restrict__ ctx)
{
    __shared__ float al_s[8 * 100];
    const int b0  = blockIdx.x * 8;
    const int tid = threadIdx.x;
    for (int v = tid; v < 800; v += 256) {
        int r = v / 100, l = v - r * 100;
        al_s[r * 100 + l] = scores[(size_t)l * BB + b0 + r];
    }
    __syncthreads();
    if (tid < 8) {
        float m = -1e30f;
        for (int l = 0; l < LL; ++l) m = fmaxf(m, al_s[tid * 100 + l]);
        float s = 0.f;
        for (int l = 0; l < LL; ++l) { float e = expf(al_s[tid * 100 + l] - m); al_s[tid * 100 + l] = e; s += e; }
        float inv = 1.f / s;
        for (int l = 0; l < LL; ++l) al_s[tid * 100 + l] *= inv;
    }
    __syncthreads();
    float acc[8] = {};
    for (int l = 0; l < LL; ++l) {
        const float* er = enc_out + (size_t)l * (BB * 256) + (size_t)b0 * 256 + tid;
        #pragma unroll
        for (int r = 0; r < 8; ++r) acc[r] += al_s[r * 100 + l] * er[r * 256];
    }
    for (int r = 0; r < 8; ++r) ctx[(size_t)(b0 + r) * 256 + tid] = acc[r];
}

// ---------------------------------------------------------------------------
// Decoder LSTM cell, same col-quad structure as enc_step Phase B.
// grid (4,64) x 512 threads.
// ---------------------------------------------------------------------------
__global__ __launch_bounds__(512) void dec_step(
    const float* __restrict__ ctxp,
    const float* __restrict__ Wdi, const float* __restrict__ Wdh,
    const float* __restrict__ bdec,
    const float* __restrict__ hd_in, float* __restrict__ hd_out,
    float* __restrict__ c_st, int first)
{
    __shared__ float ct_s[32 * 256];
    __shared__ float hd_s[32 * 256];   // reused as gate staging
    const int ns   = blockIdx.x;
    const int row0 = blockIdx.y * 32;
    const int tid  = threadIdx.x;
    {
        const float4* cg = (const float4*)(ctxp + (size_t)row0 * 256);
        for (int i = tid; i < 2048; i += 512) ((float4*)ct_s)[i] = cg[i];
    }
    if (!first) {
        const float4* hg = (const float4*)(hd_in + (size_t)row0 * 256);
        for (int i = tid; i < 2048; i += 512) ((float4*)hd_s)[i] = hg[i];
    }
    __syncthreads();
    const int lane = tid & 63, w = tid >> 6, rb = w * 4;
    const int q = lane & 15, g = lane >> 4;
    const int wcol = g * 256 + ns * 64 + q * 4;
    float acc[4][4];
    {
        float4 b4 = *(const float4*)&bdec[wcol];
        #pragma unroll
        for (int r = 0; r < 4; ++r) {
            acc[r][0] = b4.x; acc[r][1] = b4.y; acc[r][2] = b4.z; acc[r][3] = b4.w;
        }
    }
    #pragma unroll 2
    for (int k = 0; k < 256; k += 4) {
        float4 cv[4];
        #pragma unroll
        for (int r = 0; r < 4; ++r) cv[r] = *(const float4*)&ct_s[(rb + r) * 256 + k];
        #pragma unroll
        for (int kk = 0; kk < 4; ++kk) {
            float4 wv = *(const float4*)&Wdi[(size_t)(k + kk) * 1024 + wcol];
            #pragma unroll
            for (int r = 0; r < 4; ++r) {
                float e = COMP(cv[r], kk);
                acc[r][0] += e * wv.x; acc[r][1] += e * wv.y;
                acc[r][2] += e * wv.z; acc[r][3] += e * wv.w;
            }
        }
    }
    if (!first) {
        #pragma unroll 2
        for (int k = 0; k < 256; k += 4) {
            float4 hv[4];
            #pragma unroll
            for (int r = 0; r < 4; ++r) hv[r] = *(const float4*)&hd_s[(rb + r) * 256 + k];
            #pragma unroll
            for (int kk = 0; kk < 4; ++kk) {
                float4 wv = *(const float4*)&Wdh[(size_t)(k + kk) * 1024 + wcol];
                #pragma unroll
                for (int r = 0; r < 4; ++r) {
                    float e = COMP(hv[r], kk);
                    acc[r][0] += e * wv.x; acc[r][1] += e * wv.y;
                    acc[r][2] += e * wv.z; acc[r][3] += e * wv.w;
                }
            }
        }
    }
    __syncthreads();
    float* gate_s = hd_s;
    #pragma unroll
    for (int r = 0; r < 4; ++r)
        *(float4*)&gate_s[g * 2048 + (rb + r) * 64 + q * 4] =
            make_float4(acc[r][0], acc[r][1], acc[r][2], acc[r][3]);
    __syncthreads();
    #pragma unroll
    for (int r = 0; r < 4; ++r) {
        int row = rb + r;
        float gi_ = sigmoidf_(gate_s[           row * 64 + lane]);
        float gf_ = sigmoidf_(gate_s[2048 +     row * 64 + lane]);
        float gg_ = tanhf_  (gate_s[4096 +     row * 64 + lane]);
        float go_ = sigmoidf_(gate_s[6144 +     row * 64 + lane]);
        size_t ci = (size_t)(row0 + row) * 256 + ns * 64 + lane;
        float c_old = first ? 0.f : c_st[ci];
        float cn = gf_ * c_old + gi_ * gg_;
        c_st[ci]   = cn;
        hd_out[ci] = go_ * tanhf_(cn);
    }
}

// ---------------------------------------------------------------------------
// Head: fc = tanh(h_d@Wf+bf); out[:,step] = tanh(fc@Wo+bo). Block = 16 rows.
// ---------------------------------------------------------------------------
__global__ __launch_bounds__(256) void head_k(
    const float* __restrict__ hd, const float* __restrict__ Wf,
    const float* __restrict__ bf, const float* __restrict__ Wo,
    const float* __restrict__ bo, float* __restrict__ out, int step)
{
    __shared__ float hd_s[16 * 256];
    __shared__ float fc_s[16 * 128];
    const int b0  = blockIdx.x * 16;
    const int tid = threadIdx.x;
    {
        const float4* hg = (const float4*)(hd + (size_t)b0 * 256);
        for (int i = tid; i < 1024; i += 256) ((float4*)hd_s)[i] = hg[i];
    }
    __syncthreads();
    {
        const int f = tid & 127, rg = tid >> 7;
        float acc[8];
        float bfv = bf[f];
        #pragma unroll
        for (int rr = 0; rr < 8; ++rr) acc[rr] = bfv;
        const float* wp = Wf + f;
        #pragma unroll 2
        for (int k = 0; k < 256; ++k) {
            float wv = wp[k * 128];
            #pragma unroll
            for (int rr = 0; rr < 8; ++rr) acc[rr] += hd_s[(rg * 8 + rr) * 256 + k] * wv;
        }
        for (int rr = 0; rr < 8; ++rr) fc_s[(rg * 8 + rr) * 128 + f] = tanhf_(acc[rr]);
    }
    __syncthreads();
    {
        const int lane = tid & 63, w = tid >> 6;
        const float bov = bo[0];
        #pragma unroll
        for (int rr = 0; rr < 4; ++rr) {
            int r = w * 4 + rr;
            float p = fc_s[r * 128 + lane] * Wo[lane] + fc_s[r * 128 + 64 + lane] * Wo[64 + lane];
            #pragma unroll
            for (int msk = 32; msk >= 1; msk >>= 1) p += __shfl_xor(p, msk, 64);
            if (lane == 0) out[(size_t)(b0 + r) * NOUT + step] = tanhf_(p + bov);
        }
    }
}

extern "C" void kernel_launch(void* const* d_in, const int* in_sizes, int n_in,
                              void* d_out, int out_size, void* d_ws, size_t ws_size,
                              hipStream_t stream)
{
    const float* x    = (const float*)d_in[0];
    const float* Wa   = (const float*)d_in[1];
    const float* ba   = (const float*)d_in[2];
    const float* Wi   = (const float*)d_in[3];
    const float* Wh   = (const float*)d_in[4];
    const float* be   = (const float*)d_in[5];
    const float* Wd   = (const float*)d_in[6];
    const float* bd   = (const float*)d_in[7];
    const float* Wl   = (const float*)d_in[8];
    const float* bl   = (const float*)d_in[9];
    const float* Wdi  = (const float*)d_in[10];
    const float* Wdh  = (const float*)d_in[11];
    const float* bdec = (const float*)d_in[12];
    const float* Wf   = (const float*)d_in[13];
    const float* bf   = (const float*)d_in[14];
    const float* Wo   = (const float*)d_in[15];
    const float* bo   = (const float*)d_in[16];
    float* out = (float*)d_out;

    // ws layout (floats): enc_out | c_enc | hd0 | hd1 | c_d | ctx | scores  (~221 MB)
    const size_t f_enc    = (size_t)LL * BB * EE;
    const size_t f_state  = (size_t)BB * EE;
    const size_t f_scores = (size_t)LL * BB;
    const size_t base_f   = f_enc + 5 * f_state + f_scores;

    float* ws      = (float*)d_ws;
    float* enc_out = ws;
    float* c_enc   = enc_out + f_enc;
    float* hd0     = c_enc + f_state;
    float* hd1     = hd0 + f_state;
    float* c_d     = hd1 + f_state;
    float* ctx     = c_d + f_state;
    float* scores  = ctx + f_state;

    if (ws_size < base_f * sizeof(float)) return;   // diagnostic clean-fail

    dim3 egrid(4, 64);
    for (int t = 0; t < LL; ++t) {
        const float* h_in = (t == 0) ? enc_out : enc_out + (size_t)(t - 1) * BB * EE;
        float* h_out = enc_out + (size_t)t * BB * EE;
        enc_step<<<egrid, 512, 0, stream>>>(x, Wa, ba, Wi, Wh, be,
                                            h_in, h_out, c_enc, t, t == 0 ? 1 : 0);
    }

    float* hbuf[2] = { hd0, hd1 };
    for (int s = 0; s < NOUT; ++s) {
        const float* hd_in = (s == 0) ? hd0 : hbuf[(s + 1) & 1];
        float* hd_out = hbuf[s & 1];
        scores_fused<<<dim3(BB / 16, 4), 256, 0, stream>>>(
            enc_out, Wd, bd, Wl, bl, hd_in, scores, s == 0);
        softmax_ctx<<<BB / 8, 256, 0, stream>>>(scores, enc_out, ctx);
        dec_step<<<dim3(4, 64), 512, 0, stream>>>(ctx, Wdi, Wdh, bdec, hd_in, hd_out, c_d, s == 0);
        head_k<<<BB / 16, 256, 0, stream>>>(hd_out, Wf, bf, Wo, bo, out, s);
    }
}